// Round 9
// baseline (186.806 us; speedup 1.0000x reference)
//
#include <hip/hip_runtime.h>
#include <stdint.h>

typedef unsigned long long u64;

#define B_ 4
#define N_ 49104
#define C_ 90
#define NCLS (B_ * C_)        // 360
#define MAXK 100
#define THR 0.01f
#define NBH 288               // hot histogram bins: fine-bins [1760,2048) for scores in (0.93,1)
#define BINLO 1760
#define KCAP 640              // karr: sorted prefix (<=512) / cold red (512) / merge mk+selk (612)
#define PTGT 448              // prefix target candidate count
#define PCAP 512              // prefix hard cap
#define ACH 128               // anchors per select block (r7)
#define NCH ((N_ + ACH - 1) / ACH)   // 384
#define CAPC 32               // per-(class, select-block) LDS capacity (hits ~1.3/block at t0=0.99)
#define NBIN_M 1280           // merge bins (r7)
#define BINBASE 0x3F6E0000u   // float bits 0.9296875 (valid for t0 >= 0.93)
#define BINSH_M 10
#define T0 0.99f              // M ~ 491 +/- 22 per class; greedy needs ~230-300 (r15 evidence: 448 sufficed)

// ---------- exact fp32 math matching the numpy/jax reference ----------
__device__ __forceinline__ float area_of(float y1, float x1, float y2, float x2) {
#pragma clang fp contract(off)
  return (y2 - y1) * (x2 - x1);
}

// Division-free EXACT equivalent of  RN32(inter/denom) > 0.1f.
// denom >= 1e-8 > 0 always. 0.1f = 0x3DCCCCCD (odd mantissa); next up is
// 0x3DCCCCCE (even). Ties-to-even rounds the exact midpoint UP, so
//   RN32(inter/denom) > 0.1f  <=>  inter/denom >= MID,  MID = 26843547/2^28.
// MID has 25 mantissa bits, denom 24 -> MID*(double)denom is EXACT (<=49 bits),
// and (double)inter is exact, so the comparison is bit-exact vs the reference.
#define IOU_MID (26843547.0 / 268435456.0)

// aa = SELECTED (kept) box area, ba = candidate area (reference arg order)
__device__ __forceinline__ bool iou_gt(float ay1, float ax1, float ay2, float ax2, float aa,
                                       float by1, float bx1, float by2, float bx2, float ba) {
#pragma clang fp contract(off)
  float y1 = fmaxf(ay1, by1);
  float x1 = fmaxf(ax1, bx1);
  float y2 = fminf(ay2, by2);
  float x2 = fminf(ax2, bx2);
  float inter = fmaxf(y2 - y1, 0.0f) * fmaxf(x2 - x1, 0.0f);
  float denom = aa + ba - inter + 1e-8f;
  return (double)inter >= IOU_MID * (double)denom;
}

__device__ __forceinline__ u64 umax64(u64 a, u64 b) { return a > b ? a : b; }

__device__ __forceinline__ u64 shfl_xor_u64(u64 v, int m) {
  int lo = __shfl_xor((int)(unsigned)v, m);
  int hi = __shfl_xor((int)(unsigned)(v >> 32), m);
  return ((u64)(unsigned)hi << 32) | (u64)(unsigned)lo;
}

__device__ __forceinline__ int key2bin_m(u64 k) {
  int d = (int)((unsigned)(k >> 32) - BINBASE);
  int bin = d >> BINSH_M;
  if (d < 0) bin = 0;
  if (bin > NBIN_M - 1) bin = NBIN_M - 1;
  return bin;
}

// ---------- kernel S (r7-verbatim, t0=0.99): slab read -> per-class LDS bins ----------
__global__ __launch_bounds__(256) void select_kernel(const float* __restrict__ cls,
                                                     u64* __restrict__ keybuf,
                                                     unsigned* __restrict__ cnt,
                                                     int capsel, float t0) {
  __shared__ u64 ll[C_ * CAPC];        // 23040 B
  __shared__ unsigned lcnt[C_];
  __shared__ unsigned base_s[C_];
  int blk = blockIdx.x;
  int b = blk / NCH, ch = blk - b * NCH;
  int a0 = ch * ACH;
  int aEnd = a0 + ACH; if (aEnd > N_) aEnd = N_;
  int e0 = a0 * C_;                    // byte offset a0*360: 16B-aligned
  int nelem = (aEnd - a0) * C_;
  int tid = threadIdx.x;

  for (int i = tid; i < C_; i += 256) lcnt[i] = 0u;
  __syncthreads();

  const float4* src4 = (const float4*)(cls + (size_t)b * N_ * C_ + e0);
  int n4 = nelem >> 2;
  for (int i4 = tid; i4 < n4; i4 += 256) {
    float4 v = src4[i4];
#pragma unroll
    for (int j = 0; j < 4; ++j) {
      float s = (&v.x)[j];
      if (s > t0) {
        int e = e0 + i4 * 4 + j;
        unsigned n = (unsigned)e / (unsigned)C_;
        unsigned c = (unsigned)e - n * (unsigned)C_;
        u64 key = ((u64)__float_as_uint(s) << 32) | (u64)(0xFFFFFFFFu - n);
        unsigned pos = atomicAdd(&lcnt[c], 1u);
        if (pos < CAPC) {
          ll[c * CAPC + pos] = key;
        } else {                       // LDS overflow (p astronomically small): exact spill
          unsigned g = (unsigned)(b * C_) + c;
          unsigned gp = atomicAdd(&cnt[g * 16], 1u);
          if (gp < (unsigned)capsel) keybuf[(size_t)g * capsel + gp] = key;
        }
      }
    }
  }
  __syncthreads();

  if (tid < C_) {
    unsigned cc = lcnt[tid]; if (cc > CAPC) cc = CAPC;
    base_s[tid] = atomicAdd(&cnt[(b * C_ + tid) * 16], cc);
  }
  __syncthreads();

  for (int i = tid; i < C_ * CAPC; i += 256) {
    int c = i >> 5, j = i & 31;
    unsigned cc = lcnt[c]; if (cc > CAPC) cc = CAPC;
    if ((unsigned)j < cc) {
      unsigned pos = base_s[c] + (unsigned)j;
      if (pos < (unsigned)capsel)
        keybuf[(size_t)(b * C_ + c) * capsel + pos] = ll[i];
    }
  }
}

// ---------- kernel A (r16): small-pool prefix sort + rotating-pop greedy + fused merge ----------
// 512 threads/block, one block per (b,c). M ~ 491 keys; top ~448 scattered +
// rank-sorted via a 288-bin histogram; tail covered by the exact cold-path
// continuation (teff = bin bound / t0). Greedy pops one 512-window by owning
// wave. Classes pre-accumulate merge histogram into global mhist; last block
// per batch merges from it. Bit-exact greedy order throughout.
__global__ __launch_bounds__(512) void nms_kernel(const float* __restrict__ boxes,
                                                  const float* __restrict__ cls,
                                                  const u64* __restrict__ keybuf,
                                                  const unsigned* __restrict__ cnt,
                                                  unsigned* __restrict__ done,
                                                  unsigned* __restrict__ mhist,
                                                  int capsel, float t0,
                                                  u64* __restrict__ keepkeys,
                                                  int* __restrict__ nk_arr,
                                                  float* __restrict__ out) {
  int gcls = blockIdx.x;
  int b = gcls / C_, c = gcls - b * C_;
  __shared__ u64 karr[KCAP];           //  5 KB sorted prefix; cold red; merge mk+selk
  __shared__ unsigned hist[NBH];       //  1.2 KB
  __shared__ unsigned sfx[NBH];        //  1.2 KB
  __shared__ unsigned histm[NBIN_M];   //  5 KB merge
  __shared__ unsigned sfxm[NBIN_M];    //  5 KB merge
  __shared__ float4 kb[MAXK];          //  kept boxes
  __shared__ float ka[MAXK];           //  kept areas
  __shared__ u64 kkey_lds[MAXK];       //  kept keys (LDS mirror for mhist accumulation)
  __shared__ unsigned wsum[8];
  __shared__ int sh_cnt[8];            //  per-slice cumulative keep counts
  __shared__ int sh_b1, sh_pl;         //  cut bin (local), prefix length
  __shared__ int sh_last, sh_thr;
  __shared__ unsigned sh_cc;
  int tid = threadIdx.x;
  int lane = tid & 63;
  int wid = tid >> 6;

  for (int i = tid; i < MAXK; i += 512) {
    keepkeys[(size_t)gcls * MAXK + i] = 0ull;
    kkey_lds[i] = 0ull;
  }
  for (int i = tid; i < NBH; i += 512) hist[i] = 0u;
  if (tid == 0) sh_b1 = -1;
  __syncthreads();

  unsigned Mraw = cnt[gcls * 16];
  bool overflow = (Mraw > (unsigned)capsel);   // p ~ 0 at t0=0.99: exact brute force below
  int M = overflow ? 0 : (int)Mraw;

  const u64* src = keybuf + (size_t)gcls * capsel;

  // Phase A: histogram (288 bins); keys cached in registers for Phase C
  const int PK = 4096 / 512;           // 8 keys/thread capacity (M ~ 491 -> mostly 1 live)
  u64 kreg[PK];
#pragma unroll
  for (int q = 0; q < PK; ++q) {
    kreg[q] = 0ull;
    int i = q * 512 + tid;
    if (i < M) {
      kreg[q] = src[i];
      int bin = (int)((unsigned)(kreg[q] >> 44) & 2047) - BINLO;
      if (bin < 0) bin = 0;            // unreachable for s > 0.93; monotone clamp
      atomicAdd(&hist[bin], 1u);
    }
  }
  __syncthreads();

  // Phase B: inclusive suffix sum over 288 bins (descending ownership, 5 waves)
  {
    unsigned psum = (tid < NBH) ? hist[NBH - 1 - tid] : 0u;
    unsigned incl = psum;
#pragma unroll
    for (int s = 1; s < 64; s <<= 1) {
      unsigned v = (unsigned)__shfl_up((int)incl, s);
      if (lane >= s) incl += v;
    }
    if (lane == 63 && wid < 5) wsum[wid] = incl;
    __syncthreads();
    if (tid < NBH) {
      unsigned base2 = 0;
      for (int w2 = 0; w2 < wid; ++w2) base2 += wsum[w2];
      sfx[NBH - 1 - tid] = base2 + incl;
    }
  }
  __syncthreads();

  // Phase B2: cut bin b1 = largest local bin with sfx[b1] >= min(M, PTGT)
  if (M > 0 && tid < NBH) {
    int target = M < PTGT ? M : PTGT;
    if ((int)sfx[tid] >= target) atomicMax(&sh_b1, tid);
  }
  __syncthreads();
  if (tid == 0) {
    int b1 = sh_b1;                    // >= 0 whenever M > 0
    int pl = 0;
    if (M > 0) {
      pl = (int)sfx[b1];
      if (pl > PCAP) {                 // freak fat bin: exclude it
        ++b1;
        pl = (b1 < NBH) ? (int)sfx[b1] : 0;
      }
    }
    sh_b1 = b1; sh_pl = pl;
  }
  __syncthreads();
  int b1 = sh_b1;
  int prefix = sh_pl;

  // Phase C: counting-scatter ONLY keys with bin >= b1 (prefix <= PCAP)
#pragma unroll
  for (int q = 0; q < PK; ++q) {
    int i = q * 512 + tid;
    if (i < M) {
      u64 k = kreg[q];
      int bin = (int)((unsigned)(k >> 44) & 2047) - BINLO;
      if (bin < 0) bin = 0;
      if (bin >= b1) {
        unsigned old = atomicSub(&hist[bin], 1u);
        karr[sfx[bin] - old] = k;
      }
    }
  }
  __syncthreads();

  // Phase D: rank-permute within each bin -> karr[0..prefix) fully sorted desc.
  {
    u64 mk2 = 0ull; int mt = -1;
    if (tid < prefix) {
      u64 k = karr[tid];
      int bin = (int)((unsigned)(k >> 44) & 2047) - BINLO;
      if (bin < 0) bin = 0;
      int hi2 = (int)sfx[bin];
      int lo2 = (bin == NBH - 1) ? 0 : (int)sfx[bin + 1];
      int r = lo2;
      for (int j = lo2; j < hi2; ++j) r += (karr[j] > k);  // keys unique
      mk2 = k; mt = r;
    }
    __syncthreads();
    if (mt >= 0) karr[mt] = mk2;
  }
  __syncthreads();

  const float4* bx4 = (const float4*)(boxes + (size_t)b * N_ * 4);

  // ---- single-window rotating-pop greedy over the sorted prefix ----
  int seen = 0;
  if (prefix > 0) {
    bool have = tid < prefix;
    float4 cb = make_float4(0.f, 0.f, 0.f, 0.f);
    float ca = 0.f;
    if (have) {
      u64 k = karr[tid];
      cb = bx4[0xFFFFFFFFu - (unsigned)(k & 0xFFFFFFFFull)];
      ca = area_of(cb.x, cb.y, cb.z, cb.w);
    }
    u64 alive = __ballot(have);

    int nslice = (prefix + 63) >> 6;
    for (int s = 0; s < nslice; ++s) {
      if (wid == s) {
        // ---- this wave pops its own slice (4 shfls + exact area recompute) ----
        int nkl = seen;
        int slo = s << 6;
        while (alive != 0ull && nkl < MAXK) {
          int bit = __ffsll((long long)alive) - 1;
          float sy1 = __shfl(cb.x, bit);
          float sx1 = __shfl(cb.y, bit);
          float sy2 = __shfl(cb.z, bit);
          float sx2 = __shfl(cb.w, bit);
          float sa  = area_of(sy1, sx1, sy2, sx2);  // bit-exact == owner's ca
          if (lane == 0) {
            u64 key = karr[slo + bit];
            unsigned anchor = 0xFFFFFFFFu - (unsigned)(key & 0xFFFFFFFFull);
            unsigned flat = anchor * C_ + (unsigned)c;
            u64 kk2 = (key & 0xFFFFFFFF00000000ull) | (u64)(0xFFFFFFFFu - flat);
            keepkeys[(size_t)gcls * MAXK + nkl] = kk2;
            kkey_lds[nkl] = kk2;
            kb[nkl] = make_float4(sy1, sx1, sy2, sx2);
            ka[nkl] = sa;
          }
          ++nkl;
          alive &= ~__ballot(iou_gt(sy1, sx1, sy2, sx2, sa,
                                    cb.x, cb.y, cb.z, cb.w, ca));
          // self-bit always cleared (self-IOU ~ 1 > 0.1)
        }
        if (lane == 0) sh_cnt[s] = nkl;
        seen = nkl;
      }
      __syncthreads();                 // publishes kb/ka/sh_cnt[s] to all waves
      int nkNew = (wid == s) ? seen : sh_cnt[s];
      if (nkNew >= MAXK) { seen = nkNew; break; }
      if (wid > s && nkNew > seen) {
        // ---- apply slice-s keeps to own alive mask (parallel across waves) ----
        bool d2 = false;
        for (int j = seen; j < nkNew; ++j) {
          float4 sb = kb[j]; float sa = ka[j];
          d2 |= iou_gt(sb.x, sb.y, sb.z, sb.w, sa,
                       cb.x, cb.y, cb.z, cb.w, ca);
        }
        alive &= __ballot(!d2);
      }
      seen = nkNew;
    }
  }

  // ---- inline exact continuation (cold path; reuses karr as reduction buf) ----
  int nkF = seen;
  if (nkF < MAXK) {
    float teff;
    if (overflow)           teff = 2.0f;
    else if (prefix == 0)   teff = 2.0f;   // M==0 or degenerate: scan everything
    else if (prefix < M)    teff = __uint_as_float(0x3F000000u | ((((unsigned)(b1 + BINLO)) << 12) - 1u));
    else                    teff = t0;
    const float* sbase = cls + (size_t)b * N_ * C_ + c;
    const float* bx = boxes + (size_t)b * N_ * 4;
    u64* kkp = keepkeys + (size_t)gcls * MAXK;
    u64* red = karr;                   // karr no longer needed
    int nk2 = nkF;
    while (nk2 < MAXK) {
      u64 best = 0ull;
      for (int n = tid; n < N_; n += 512) {
        float s = sbase[(size_t)n * C_];
        if (s > THR && s <= teff) {
          float y1 = bx[(size_t)n * 4 + 0], x1 = bx[(size_t)n * 4 + 1];
          float y2 = bx[(size_t)n * 4 + 2], x2 = bx[(size_t)n * 4 + 3];
          float ar = area_of(y1, x1, y2, x2);
          bool ov = false;
          for (int j = 0; j < nk2; ++j) {
            float4 kbj = kb[j];
            if (iou_gt(kbj.x, kbj.y, kbj.z, kbj.w, ka[j], y1, x1, y2, x2, ar)) { ov = true; break; }
          }
          if (!ov) {
            u64 key = ((u64)__float_as_uint(s) << 32) | (u64)(0xFFFFFFFFu - (unsigned)n);
            best = umax64(best, key);
          }
        }
      }
      red[tid] = best;
      __syncthreads();
      for (int sft = 256; sft > 0; sft >>= 1) {
        if (tid < sft) red[tid] = umax64(red[tid], red[tid + sft]);
        __syncthreads();
      }
      u64 sel = red[0];
      __syncthreads();
      if (sel == 0ull) {
        if (tid == 0) {  // exhausted before MAXK: reference quirk -> keep[anchor 0] = False
          unsigned target2 = 0xFFFFFFFFu - (unsigned)c;  // anchor 0 -> flat == c
          for (int j = 0; j < nk2; ++j)
            if ((unsigned)(kkp[j] & 0xFFFFFFFFull) == target2) { kkp[j] = 0ull; kkey_lds[j] = 0ull; }
        }
        break;
      }
      unsigned anchor = 0xFFFFFFFFu - (unsigned)(sel & 0xFFFFFFFFull);
      if (tid == 0) {
        float y1 = bx[(size_t)anchor * 4 + 0], x1 = bx[(size_t)anchor * 4 + 1];
        float y2 = bx[(size_t)anchor * 4 + 2], x2 = bx[(size_t)anchor * 4 + 3];
        kb[nk2] = make_float4(y1, x1, y2, x2);
        ka[nk2] = area_of(y1, x1, y2, x2);
        unsigned flat = anchor * C_ + (unsigned)c;
        u64 kk2 = (sel & 0xFFFFFFFF00000000ull) | (u64)(0xFFFFFFFFu - flat);
        kkp[nk2] = kk2;
        kkey_lds[nk2] = kk2;
      }
      ++nk2;
      __syncthreads();
    }
    nkF = nk2;
  }
  if (tid == 0) nk_arr[gcls] = nkF;
  __syncthreads();                     // kkey_lds final & visible to all threads

  // ---- pre-accumulate merge histogram (overlaps across blocks) ----
  for (int i = tid; i < nkF; i += 512) {
    u64 k = kkey_lds[i];
    if (k != 0ull) atomicAdd(&mhist[b * NBIN_M + key2bin_m(k)], 1u);
  }
  __syncthreads();

  // ---- fan-in: last finishing block of batch b runs merge inline ----
  if (tid == 0) {
    __threadfence();                   // release keepkeys/nk_arr/mhist writes
    sh_last = (atomicAdd(&done[b], 1u) == (unsigned)(C_ - 1)) ? 1 : 0;
  }
  __syncthreads();
  if (!sh_last) return;
  __threadfence();                     // acquire other blocks' writes

  // ===== merge (prebuilt histogram + threshold + 1-barrier rank sort) =====
  {
    const u64* kk = keepkeys + (size_t)b * C_ * MAXK;
    const int TOT = C_ * MAXK;         // 9000
    u64* mk = karr;                    // [0..512)
    u64* selk = karr + 512;            // [0..MAXK)

    for (int i = tid; i < NBIN_M; i += 512) histm[i] = mhist[b * NBIN_M + i];
    for (int r = tid; r < MAXK; r += 512) selk[r] = 0ull;
    if (tid == 0) { sh_thr = -1; sh_cc = 0u; }
    __syncthreads();

    const int Wm = 3;                  // 512*3 >= 1280 bins
    int j0 = tid * Wm;
    unsigned psum = 0;
#pragma unroll
    for (int q = 0; q < Wm; ++q) {
      int bin = NBIN_M - 1 - (j0 + q);
      if (bin >= 0) psum += histm[bin];
    }
    unsigned incl = psum;
#pragma unroll
    for (int s = 1; s < 64; s <<= 1) {
      unsigned v = (unsigned)__shfl_up((int)incl, s);
      if (lane >= s) incl += v;
    }
    if (lane == 63) wsum[wid] = incl;
    __syncthreads();
    unsigned base = incl - psum;
    for (int w2 = 0; w2 < wid; ++w2) base += wsum[w2];
    unsigned running = base;
    int mythr = -1;
#pragma unroll
    for (int q = 0; q < Wm; ++q) {
      int bin = NBIN_M - 1 - (j0 + q);
      if (bin >= 0) {
        running += histm[bin];
        sfxm[bin] = running;
        if (mythr < 0 && running >= (unsigned)MAXK) mythr = bin;
      }
    }
    if (mythr >= 0) atomicMax(&sh_thr, mythr);
    __syncthreads();

    int thr = sh_thr; if (thr < 0) thr = 0;
    unsigned S = sfxm[thr];

    if (S <= 512u) {
      for (int i = tid; i < TOT; i += 512) {
        u64 k = kk[i];
        if (k != 0ull && key2bin_m(k) >= thr) {
          unsigned pos = atomicAdd(&sh_cc, 1u);
          mk[pos] = k;
        }
      }
      __syncthreads();
      // rank sort: keys unique & nonzero -> unique ranks; top-MAXK to selk
      u64 myk = (tid < (int)S) ? mk[tid] : 0ull;
      int r = 0;
      for (int j = 0; j < (int)S; ++j) r += (mk[j] > myk);
      __syncthreads();
      if (tid < (int)S && r < MAXK) selk[r] = myk;
      __syncthreads();
    } else {
      // degenerate tie flood: exact serial tournament on wave 0
      if (wid == 0) {
        int c0 = lane, c1 = lane + 64;
        int len0 = (c0 < C_) ? nk_arr[b * C_ + c0] : 0;
        int len1 = (c1 < C_) ? nk_arr[b * C_ + c1] : 0;
        int h0 = 0, h1 = 0;
        auto fetchc = [&](int cc, int& h, int len) -> u64 {
          while (h < len) {
            u64 k = kk[(size_t)cc * MAXK + h];
            if (k != 0ull) return k;
            ++h;
          }
          return 0ull;
        };
        u64 cand0 = (c0 < C_) ? fetchc(c0, h0, len0) : 0ull;
        u64 cand1 = (c1 < C_) ? fetchc(c1, h1, len1) : 0ull;
        for (int r2 = 0; r2 < MAXK; ++r2) {
          u64 my = umax64(cand0, cand1);
          u64 g = my;
#pragma unroll
          for (int m = 1; m < 64; m <<= 1) g = umax64(g, shfl_xor_u64(g, m));
          if (lane == 0) selk[r2] = g;
          if (g != 0ull && my == g) {
            if (cand0 == g) { ++h0; cand0 = fetchc(c0, h0, len0); }
            else            { ++h1; cand1 = fetchc(c1, h1, len1); }
          }
        }
      }
      __syncthreads();
    }

    for (int r2 = tid; r2 < MAXK; r2 += 512) {
      u64 s = selk[r2];
      float oy1, ox1, oy2, ox2, sc, lb;
      if (s != 0ull) {
        unsigned flat = 0xFFFFFFFFu - (unsigned)(s & 0xFFFFFFFFull);
        unsigned anchor = flat / C_;
        unsigned label = flat - anchor * C_;
        sc = __uint_as_float((unsigned)(s >> 32));
        const float4 bp = ((const float4*)(boxes + (size_t)b * N_ * 4))[anchor];
        oy1 = bp.x; ox1 = bp.y; oy2 = bp.z; ox2 = bp.w;
        lb = (float)label;
      } else {
        oy1 = ox1 = oy2 = ox2 = -1.0f; sc = -1.0f; lb = -1.0f;
      }
      float* bo = out + ((size_t)b * MAXK + r2) * 4;
      bo[0] = oy1; bo[1] = ox1; bo[2] = oy2; bo[3] = ox2;
      out[(size_t)B_ * MAXK * 4 + b * MAXK + r2] = sc;
      out[(size_t)B_ * MAXK * 4 + B_ * MAXK + b * MAXK + r2] = lb;
    }
  }
}

extern "C" void kernel_launch(void* const* d_in, const int* in_sizes, int n_in,
                              void* d_out, int out_size, void* d_ws, size_t ws_size,
                              hipStream_t stream) {
  const float* boxes = (const float*)d_in[0];   // [B,N,4]
  const float* cls = (const float*)d_in[1];     // [B,N,C]
  char* ws = (char*)d_ws;

  // capacity tier by available workspace; t0=0.99 for all (M ~ 491 << 1024)
  int capsel;
  auto need_for = [](int cap) -> size_t {
    return 43584 + (size_t)NCLS * cap * 8 + 288000 + 1440;
  };
  if (ws_size >= need_for(4096))      capsel = 4096;
  else if (ws_size >= need_for(2048)) capsel = 2048;
  else                                capsel = 1024;

  // layout: cnt (23040, 64B-strided) | done[4]+pad (64) | mhist[4][1280] (20480)
  //         | keybuf | keepkeys | nk_arr
  unsigned* cnt = (unsigned*)ws;
  unsigned* done = (unsigned*)(ws + 23040);
  unsigned* mhist = (unsigned*)(ws + 23104);
  u64* keybuf = (u64*)(ws + 43584);
  size_t off = 43584 + (size_t)NCLS * capsel * 8;
  u64* keepkeys = (u64*)(ws + off);      off += 288000;
  int* nk_arr = (int*)(ws + off);

  hipMemsetAsync(ws, 0, 43584, stream);
  select_kernel<<<B_ * NCH, 256, 0, stream>>>(cls, keybuf, cnt, capsel, T0);
  nms_kernel<<<NCLS, 512, 0, stream>>>(boxes, cls, keybuf, cnt, done, mhist, capsel, T0,
                                       keepkeys, nk_arr, (float*)d_out);
}

// Round 10
// 176.776 us; speedup vs baseline: 1.0567x; 1.0567x over previous
//
#include <hip/hip_runtime.h>
#include <stdint.h>

typedef unsigned long long u64;

#define B_ 4
#define N_ 49104
#define C_ 90
#define NCLS (B_ * C_)        // 360
#define MAXK 100
#define THR 0.01f
#define NBH 288               // hot histogram bins: fine-bins [1760,2048) for scores in (0.93,1)
#define BINLO 1760
#define KCAP 640              // karr: window (<=512) / cold red (512) / merge mk+selk (612)
#define PTGT 448              // per-window target candidate count
#define PCAP 512              // window hard cap
#define ACH 128               // anchors per select block (r7)
#define NCH ((N_ + ACH - 1) / ACH)   // 384
#define CAPC 32               // per-(class, select-block) LDS capacity; mean 8.96, +8 sigma
#define NBIN_M 1280           // merge bins (r7)
#define BINBASE 0x3F6E0000u   // float bits 0.9296875 (valid for all t0 tiers >= 0.93)
#define BINSH_M 10

// ---------- exact fp32 math matching the numpy/jax reference ----------
__device__ __forceinline__ float area_of(float y1, float x1, float y2, float x2) {
#pragma clang fp contract(off)
  return (y2 - y1) * (x2 - x1);
}

// Division-free EXACT equivalent of  RN32(inter/denom) > 0.1f.
// denom >= 1e-8 > 0 always. 0.1f = 0x3DCCCCCD (odd mantissa); next up is
// 0x3DCCCCCE (even). Ties-to-even rounds the exact midpoint UP, so
//   RN32(inter/denom) > 0.1f  <=>  inter/denom >= MID,  MID = 26843547/2^28.
// MID has 25 mantissa bits, denom 24 -> MID*(double)denom is EXACT (<=49 bits),
// and (double)inter is exact, so the comparison is bit-exact vs the reference.
#define IOU_MID (26843547.0 / 268435456.0)

// aa = SELECTED (kept) box area, ba = candidate area (reference arg order)
__device__ __forceinline__ bool iou_gt(float ay1, float ax1, float ay2, float ax2, float aa,
                                       float by1, float bx1, float by2, float bx2, float ba) {
#pragma clang fp contract(off)
  float y1 = fmaxf(ay1, by1);
  float x1 = fmaxf(ax1, bx1);
  float y2 = fminf(ay2, by2);
  float x2 = fminf(ax2, bx2);
  float inter = fmaxf(y2 - y1, 0.0f) * fmaxf(x2 - x1, 0.0f);
  float denom = aa + ba - inter + 1e-8f;
  return (double)inter >= IOU_MID * (double)denom;
}

__device__ __forceinline__ u64 umax64(u64 a, u64 b) { return a > b ? a : b; }

__device__ __forceinline__ u64 shfl_xor_u64(u64 v, int m) {
  int lo = __shfl_xor((int)(unsigned)v, m);
  int hi = __shfl_xor((int)(unsigned)(v >> 32), m);
  return ((u64)(unsigned)hi << 32) | (u64)(unsigned)lo;
}

__device__ __forceinline__ int key2bin_m(u64 k) {
  int d = (int)((unsigned)(k >> 32) - BINBASE);
  int bin = d >> BINSH_M;
  if (d < 0) bin = 0;
  if (bin > NBIN_M - 1) bin = NBIN_M - 1;
  return bin;
}

__device__ __forceinline__ int keybin_h(u64 k) {
  int bin = (int)((unsigned)(k >> 44) & 2047) - BINLO;
  if (bin < 0) bin = 0;
  if (bin > NBH - 1) bin = NBH - 1;
  return bin;
}

// ---------- kernel S (r7-verbatim): slab read -> per-class LDS bins -> bulk flush ----------
__global__ __launch_bounds__(256) void select_kernel(const float* __restrict__ cls,
                                                     u64* __restrict__ keybuf,
                                                     unsigned* __restrict__ cnt,
                                                     int capsel, float t0) {
  __shared__ u64 ll[C_ * CAPC];        // 23040 B
  __shared__ unsigned lcnt[C_];
  __shared__ unsigned base_s[C_];
  int blk = blockIdx.x;
  int b = blk / NCH, ch = blk - b * NCH;
  int a0 = ch * ACH;
  int aEnd = a0 + ACH; if (aEnd > N_) aEnd = N_;
  int e0 = a0 * C_;                    // byte offset a0*360: 16B-aligned
  int nelem = (aEnd - a0) * C_;
  int tid = threadIdx.x;

  for (int i = tid; i < C_; i += 256) lcnt[i] = 0u;
  __syncthreads();

  const float4* src4 = (const float4*)(cls + (size_t)b * N_ * C_ + e0);
  int n4 = nelem >> 2;
  for (int i4 = tid; i4 < n4; i4 += 256) {
    float4 v = src4[i4];
#pragma unroll
    for (int j = 0; j < 4; ++j) {
      float s = (&v.x)[j];
      if (s > t0) {
        int e = e0 + i4 * 4 + j;
        unsigned n = (unsigned)e / (unsigned)C_;
        unsigned c = (unsigned)e - n * (unsigned)C_;
        u64 key = ((u64)__float_as_uint(s) << 32) | (u64)(0xFFFFFFFFu - n);
        unsigned pos = atomicAdd(&lcnt[c], 1u);
        if (pos < CAPC) {
          ll[c * CAPC + pos] = key;
        } else {                       // LDS overflow (p ~ 1e-13): exact global spill
          unsigned g = (unsigned)(b * C_) + c;
          unsigned gp = atomicAdd(&cnt[g * 16], 1u);
          if (gp < (unsigned)capsel) keybuf[(size_t)g * capsel + gp] = key;
        }
      }
    }
  }
  __syncthreads();

  if (tid < C_) {
    unsigned cc = lcnt[tid]; if (cc > CAPC) cc = CAPC;
    base_s[tid] = atomicAdd(&cnt[(b * C_ + tid) * 16], cc);
  }
  __syncthreads();

  for (int i = tid; i < C_ * CAPC; i += 256) {
    int c = i >> 5, j = i & 31;
    unsigned cc = lcnt[c]; if (cc > CAPC) cc = CAPC;
    if ((unsigned)j < cc) {
      unsigned pos = base_s[c] + (unsigned)j;
      if (pos < (unsigned)capsel)
        keybuf[(size_t)(b * C_ + c) * capsel + pos] = ll[i];
    }
  }
}

// ---------- kernel A (r17): lazy-window counting sort + rotating-pop greedy + fused merge ----------
// 512 threads/block, one block per (b,c). Keys cached in registers; windows of
// ~448 keys are cut, scattered and rank-sorted ON DEMAND from the 288-bin
// histogram (common case: 1 window). The N-scan cold path survives only for
// pool exhaustion / fat-bin degeneracy. Bit-exact greedy order throughout.
__global__ __launch_bounds__(512) void nms_kernel(const float* __restrict__ boxes,
                                                  const float* __restrict__ cls,
                                                  const u64* __restrict__ keybuf,
                                                  const unsigned* __restrict__ cnt,
                                                  unsigned* __restrict__ done,
                                                  int capsel, float t0,
                                                  u64* __restrict__ keepkeys,
                                                  int* __restrict__ nk_arr,
                                                  float* __restrict__ out) {
  int gcls = blockIdx.x;
  int b = gcls / C_, c = gcls - b * C_;
  __shared__ u64 karr[KCAP];           //  5 KB window keys; cold red; merge mk+selk
  __shared__ unsigned hist[NBH];       //  1.2 KB (drained per-window by scatter)
  __shared__ unsigned sfx[NBH];        //  1.2 KB suffix counts (stable)
  __shared__ unsigned histm[NBIN_M];   //  5 KB merge overlay
  __shared__ unsigned sfxm[NBIN_M];    //  5 KB merge overlay
  __shared__ float4 kb[MAXK];          //  kept boxes
  __shared__ float ka[MAXK];           //  kept areas
  __shared__ unsigned wsum[8];
  __shared__ int sh_cnt[8];            //  per-slice cumulative keep counts
  __shared__ int sh_b1, sh_run, sh_over;
  __shared__ int sh_last, sh_thr;
  __shared__ unsigned sh_cc;
  int tid = threadIdx.x;
  int lane = tid & 63;
  int wid = tid >> 6;

  for (int i = tid; i < MAXK; i += 512) keepkeys[(size_t)gcls * MAXK + i] = 0ull;
  for (int i = tid; i < NBH; i += 512) hist[i] = 0u;
  if (tid == 0) sh_over = 0;
  __syncthreads();

  unsigned Mraw = cnt[gcls * 16];
  bool overflow = (Mraw > (unsigned)capsel);   // p < 1e-25: exact full brute force below
  int M = overflow ? 0 : (int)Mraw;

  const u64* src = keybuf + (size_t)gcls * capsel;

  // Phase A: histogram (288 bins); keys cached in registers
  const int PK = 4096 / 512;           // 8 keys/thread (max capsel tier)
  u64 kreg[PK];
#pragma unroll
  for (int q = 0; q < PK; ++q) {
    kreg[q] = 0ull;
    int i = q * 512 + tid;
    if (i < M) {
      kreg[q] = src[i];
      atomicAdd(&hist[keybin_h(kreg[q])], 1u);
    }
  }
  __syncthreads();

  // Phase B: inclusive suffix sum over 288 bins: sfx[bin] = #keys in bins >= bin
  {
    unsigned psum = (tid < NBH) ? hist[NBH - 1 - tid] : 0u;
    unsigned incl = psum;
#pragma unroll
    for (int s = 1; s < 64; s <<= 1) {
      unsigned v = (unsigned)__shfl_up((int)incl, s);
      if (lane >= s) incl += v;
    }
    if (lane == 63 && wid < 5) wsum[wid] = incl;
    __syncthreads();
    if (tid < NBH) {
      unsigned base2 = 0;
      for (int w2 = 0; w2 < wid; ++w2) base2 += wsum[w2];
      sfx[NBH - 1 - tid] = base2 + incl;
    }
  }
  __syncthreads();

  const float4* bx4 = (const float4*)(boxes + (size_t)b * N_ * 4);

  // ---- lazy-window greedy loop ----
  int seen = 0;                        // keeps so far (uniform across block)
  int ext = 0;                         // keys consumed (== sfx[bhi])
  int bhi = NBH;                       // exclusive upper bin bound of next window
  while (ext < M && seen < MAXK) {
    // cut: largest bin b1 < bhi with sfx[b1] >= ext + min(rem, PTGT)
    if (tid == 0) sh_b1 = -1;
    __syncthreads();
    int rem = M - ext;
    int target = rem < PTGT ? rem : PTGT;
    {
      int mymax = -1;
      if (tid < NBH && tid < bhi && (int)sfx[tid] >= ext + target) mymax = tid;
      for (int m = 32; m > 0; m >>= 1) {
        int o = __shfl_xor(mymax, m);
        mymax = o > mymax ? o : mymax;
      }
      if (lane == 0 && mymax >= 0) atomicMax(&sh_b1, mymax);
    }
    __syncthreads();
    if (tid == 0) {
      int b1 = sh_b1;                  // exists: sfx[0] == M >= ext + target
      int run = (int)sfx[b1] - ext;
      int blo = b1;
      if (run > PCAP) {                // fat crossing bin: exclude it
        blo = b1 + 1;
        run = (blo < NBH) ? (int)sfx[blo] - ext : 0;
      }
      if (run == 0) sh_over = 1;       // single bin > PCAP keys (degenerate ties)
      sh_b1 = blo; sh_run = run;
    }
    __syncthreads();
    if (sh_over) break;
    int blo = sh_b1, run = sh_run;

    // scatter bins [blo, bhi) from kreg into karr[0..run)
#pragma unroll
    for (int q = 0; q < PK; ++q) {
      int i = q * 512 + tid;
      if (i < M) {
        u64 k = kreg[q];
        int bin = keybin_h(k);
        if (bin >= blo && bin < bhi) {
          unsigned old = atomicSub(&hist[bin], 1u);
          karr[(int)sfx[bin] - (int)old - ext] = k;
        }
      }
    }
    __syncthreads();

    // rank-permute within each bin -> karr[0..run) fully sorted descending
    {
      u64 mk2 = 0ull; int mt = -1;
      if (tid < run) {
        u64 k = karr[tid];
        int bin = keybin_h(k);
        int hi2 = (int)sfx[bin] - ext;
        int lo2 = (bin >= NBH - 1) ? 0 : ((int)sfx[bin + 1] - ext);
        if (lo2 < 0) lo2 = 0;
        int r = lo2;
        for (int j = lo2; j < hi2; ++j) r += (karr[j] > k);  // keys unique
        mk2 = k; mt = r;
      }
      __syncthreads();
      if (mt >= 0) karr[mt] = mk2;
    }
    __syncthreads();

    // rotating-pop greedy over this window
    {
      bool have = tid < run;
      float4 cb = make_float4(0.f, 0.f, 0.f, 0.f);
      float ca = 0.f;
      if (have) {
        u64 k = karr[tid];
        cb = bx4[0xFFFFFFFFu - (unsigned)(k & 0xFFFFFFFFull)];
        ca = area_of(cb.x, cb.y, cb.z, cb.w);
      }
      // arrival: suppress by keeps [0, seen) — all waves in parallel
      bool dead = !have;
      for (int j = 0; j < seen; ++j) {
        float4 sb = kb[j]; float sa = ka[j];
        dead |= iou_gt(sb.x, sb.y, sb.z, sb.w, sa,
                       cb.x, cb.y, cb.z, cb.w, ca);
      }
      u64 alive = __ballot(!dead);

      int nslice = (run + 63) >> 6;
      for (int s = 0; s < nslice; ++s) {
        if (wid == s) {
          // ---- this wave pops its own slice (r11 single-pop body) ----
          int nkl = seen;
          int slo = s << 6;
          while (alive != 0ull && nkl < MAXK) {
            int bit = __ffsll((long long)alive) - 1;
            float sy1 = __shfl(cb.x, bit);
            float sx1 = __shfl(cb.y, bit);
            float sy2 = __shfl(cb.z, bit);
            float sx2 = __shfl(cb.w, bit);
            float sa  = __shfl(ca,   bit);
            if (lane == 0) {
              u64 key = karr[slo + bit];
              unsigned anchor = 0xFFFFFFFFu - (unsigned)(key & 0xFFFFFFFFull);
              unsigned flat = anchor * C_ + (unsigned)c;
              keepkeys[(size_t)gcls * MAXK + nkl] =
                  (key & 0xFFFFFFFF00000000ull) | (u64)(0xFFFFFFFFu - flat);
              kb[nkl] = make_float4(sy1, sx1, sy2, sx2);
              ka[nkl] = sa;
            }
            ++nkl;
            alive &= ~__ballot(iou_gt(sy1, sx1, sy2, sx2, sa,
                                      cb.x, cb.y, cb.z, cb.w, ca));
            // self-bit always cleared (self-IOU ~ 1 > 0.1)
          }
          if (lane == 0) sh_cnt[s] = nkl;
          seen = nkl;
        }
        __syncthreads();               // publishes kb/ka/sh_cnt[s] to all waves
        int nkNew = (wid == s) ? seen : sh_cnt[s];
        if (nkNew >= MAXK) { seen = nkNew; break; }
        if (wid > s && nkNew > seen) {
          // ---- apply slice-s keeps to own alive mask (parallel across waves) ----
          bool d2 = false;
          for (int j = seen; j < nkNew; ++j) {
            float4 sb = kb[j]; float sa = ka[j];
            d2 |= iou_gt(sb.x, sb.y, sb.z, sb.w, sa,
                         cb.x, cb.y, cb.z, cb.w, ca);
          }
          alive &= __ballot(!d2);
        }
        seen = nkNew;
      }
    }
    ext += run;                        // == sfx[blo]
    bhi = blo;
    __syncthreads();
  }

  // ---- inline exact continuation (cold path; reuses karr as reduction buf) ----
  int nkF = seen;
  if (nkF < MAXK) {
    float teff;
    if (overflow)      teff = 2.0f;
    else if (sh_over)  teff = __uint_as_float(0x3F000000u | ((((unsigned)(bhi + BINLO)) << 12) - 1u));
    else               teff = t0;      // pool exhausted (ext >= M)
    const float* sbase = cls + (size_t)b * N_ * C_ + c;
    const float* bx = boxes + (size_t)b * N_ * 4;
    u64* kkp = keepkeys + (size_t)gcls * MAXK;
    u64* red = karr;                   // karr no longer needed
    int nk2 = nkF;
    while (nk2 < MAXK) {
      u64 best = 0ull;
      for (int n = tid; n < N_; n += 512) {
        float s = sbase[(size_t)n * C_];
        if (s > THR && s <= teff) {
          float y1 = bx[(size_t)n * 4 + 0], x1 = bx[(size_t)n * 4 + 1];
          float y2 = bx[(size_t)n * 4 + 2], x2 = bx[(size_t)n * 4 + 3];
          float ar = area_of(y1, x1, y2, x2);
          bool ov = false;
          for (int j = 0; j < nk2; ++j) {
            float4 kbj = kb[j];
            if (iou_gt(kbj.x, kbj.y, kbj.z, kbj.w, ka[j], y1, x1, y2, x2, ar)) { ov = true; break; }
          }
          if (!ov) {
            u64 key = ((u64)__float_as_uint(s) << 32) | (u64)(0xFFFFFFFFu - (unsigned)n);
            best = umax64(best, key);
          }
        }
      }
      red[tid] = best;
      __syncthreads();
      for (int sft = 256; sft > 0; sft >>= 1) {
        if (tid < sft) red[tid] = umax64(red[tid], red[tid + sft]);
        __syncthreads();
      }
      u64 sel = red[0];
      __syncthreads();
      if (sel == 0ull) {
        if (tid == 0) {  // exhausted before MAXK: reference quirk -> keep[anchor 0] = False
          unsigned target2 = 0xFFFFFFFFu - (unsigned)c;  // anchor 0 -> flat == c
          for (int j = 0; j < nk2; ++j)
            if ((unsigned)(kkp[j] & 0xFFFFFFFFull) == target2) kkp[j] = 0ull;
        }
        break;
      }
      unsigned anchor = 0xFFFFFFFFu - (unsigned)(sel & 0xFFFFFFFFull);
      if (tid == 0) {
        float y1 = bx[(size_t)anchor * 4 + 0], x1 = bx[(size_t)anchor * 4 + 1];
        float y2 = bx[(size_t)anchor * 4 + 2], x2 = bx[(size_t)anchor * 4 + 3];
        kb[nk2] = make_float4(y1, x1, y2, x2);
        ka[nk2] = area_of(y1, x1, y2, x2);
        unsigned flat = anchor * C_ + (unsigned)c;
        kkp[nk2] = (sel & 0xFFFFFFFF00000000ull) | (u64)(0xFFFFFFFFu - flat);
      }
      ++nk2;
      __syncthreads();
    }
    nkF = nk2;
  }
  if (tid == 0) nk_arr[gcls] = nkF;

  // ---- fan-in: last finishing block of batch b runs merge inline ----
  __syncthreads();
  if (tid == 0) {
    __threadfence();                   // release all this block's global writes
    sh_last = (atomicAdd(&done[b], 1u) == (unsigned)(C_ - 1)) ? 1 : 0;
  }
  __syncthreads();
  if (!sh_last) return;
  __threadfence();                     // acquire other blocks' writes

  // ===== merge (histogram threshold + 1-barrier rank sort) =====
  {
    const u64* kk = keepkeys + (size_t)b * C_ * MAXK;
    const int TOT = C_ * MAXK;         // 9000
    u64* mk = karr;                    // [0..512)
    u64* selk = karr + 512;            // [0..MAXK)

    for (int i = tid; i < NBIN_M; i += 512) histm[i] = 0u;
    for (int r = tid; r < MAXK; r += 512) selk[r] = 0ull;
    if (tid == 0) { sh_thr = -1; sh_cc = 0u; }
    __syncthreads();
    for (int i = tid; i < TOT; i += 512) {
      u64 k = kk[i];
      if (k != 0ull) atomicAdd(&histm[key2bin_m(k)], 1u);
    }
    __syncthreads();

    const int Wm = 3;                  // 512*3 >= 1280 bins
    int j0 = tid * Wm;
    unsigned psum = 0;
#pragma unroll
    for (int q = 0; q < Wm; ++q) {
      int bin = NBIN_M - 1 - (j0 + q);
      if (bin >= 0) psum += histm[bin];
    }
    unsigned incl = psum;
#pragma unroll
    for (int s = 1; s < 64; s <<= 1) {
      unsigned v = (unsigned)__shfl_up((int)incl, s);
      if (lane >= s) incl += v;
    }
    if (lane == 63) wsum[wid] = incl;
    __syncthreads();
    unsigned base = incl - psum;
    for (int w2 = 0; w2 < wid; ++w2) base += wsum[w2];
    unsigned running = base;
    int mythr = -1;
#pragma unroll
    for (int q = 0; q < Wm; ++q) {
      int bin = NBIN_M - 1 - (j0 + q);
      if (bin >= 0) {
        running += histm[bin];
        sfxm[bin] = running;
        if (mythr < 0 && running >= (unsigned)MAXK) mythr = bin;
      }
    }
    if (mythr >= 0) atomicMax(&sh_thr, mythr);
    __syncthreads();

    int thr = sh_thr; if (thr < 0) thr = 0;
    unsigned S = sfxm[thr];

    if (S <= 512u) {
      for (int i = tid; i < TOT; i += 512) {
        u64 k = kk[i];
        if (k != 0ull && key2bin_m(k) >= thr) {
          unsigned pos = atomicAdd(&sh_cc, 1u);
          mk[pos] = k;
        }
      }
      __syncthreads();
      // rank sort: keys unique & nonzero -> unique ranks; top-MAXK to selk
      u64 myk = (tid < (int)S) ? mk[tid] : 0ull;
      int r = 0;
      for (int j = 0; j < (int)S; ++j) r += (mk[j] > myk);
      __syncthreads();
      if (tid < (int)S && r < MAXK) selk[r] = myk;
      __syncthreads();
    } else {
      // degenerate tie flood: exact serial tournament on wave 0
      if (wid == 0) {
        int c0 = lane, c1 = lane + 64;
        int len0 = (c0 < C_) ? nk_arr[b * C_ + c0] : 0;
        int len1 = (c1 < C_) ? nk_arr[b * C_ + c1] : 0;
        int h0 = 0, h1 = 0;
        auto fetchc = [&](int cc, int& h, int len) -> u64 {
          while (h < len) {
            u64 k = kk[(size_t)cc * MAXK + h];
            if (k != 0ull) return k;
            ++h;
          }
          return 0ull;
        };
        u64 cand0 = (c0 < C_) ? fetchc(c0, h0, len0) : 0ull;
        u64 cand1 = (c1 < C_) ? fetchc(c1, h1, len1) : 0ull;
        for (int r2 = 0; r2 < MAXK; ++r2) {
          u64 my = umax64(cand0, cand1);
          u64 g = my;
#pragma unroll
          for (int m = 1; m < 64; m <<= 1) g = umax64(g, shfl_xor_u64(g, m));
          if (lane == 0) selk[r2] = g;
          if (g != 0ull && my == g) {
            if (cand0 == g) { ++h0; cand0 = fetchc(c0, h0, len0); }
            else            { ++h1; cand1 = fetchc(c1, h1, len1); }
          }
        }
      }
      __syncthreads();
    }

    for (int r2 = tid; r2 < MAXK; r2 += 512) {
      u64 s = selk[r2];
      float oy1, ox1, oy2, ox2, sc, lb;
      if (s != 0ull) {
        unsigned flat = 0xFFFFFFFFu - (unsigned)(s & 0xFFFFFFFFull);
        unsigned anchor = flat / C_;
        unsigned label = flat - anchor * C_;
        sc = __uint_as_float((unsigned)(s >> 32));
        const float4 bp = ((const float4*)(boxes + (size_t)b * N_ * 4))[anchor];
        oy1 = bp.x; ox1 = bp.y; oy2 = bp.z; ox2 = bp.w;
        lb = (float)label;
      } else {
        oy1 = ox1 = oy2 = ox2 = -1.0f; sc = -1.0f; lb = -1.0f;
      }
      float* bo = out + ((size_t)b * MAXK + r2) * 4;
      bo[0] = oy1; bo[1] = ox1; bo[2] = oy2; bo[3] = ox2;
      out[(size_t)B_ * MAXK * 4 + b * MAXK + r2] = sc;
      out[(size_t)B_ * MAXK * 4 + B_ * MAXK + b * MAXK + r2] = lb;
    }
  }
}

extern "C" void kernel_launch(void* const* d_in, const int* in_sizes, int n_in,
                              void* d_out, int out_size, void* d_ws, size_t ws_size,
                              hipStream_t stream) {
  const float* boxes = (const float*)d_in[0];   // [B,N,4]
  const float* cls = (const float*)d_in[1];     // [B,N,C]
  char* ws = (char*)d_ws;

  // capacity/threshold tiers by available workspace (all t0 >= 0.93 for BINBASE validity)
  int capsel; float t0;
  auto need_for = [](int cap) -> size_t {
    return 23104 + (size_t)NCLS * cap * 8 + 288000 + 1440;
  };
  if (ws_size >= need_for(4096))      { capsel = 4096; t0 = 0.93f;  }  // M ~ 3437 +/- 57
  else if (ws_size >= need_for(2048)) { capsel = 2048; t0 = 0.962f; }  // M ~ 1866 +/- 42
  else                                { capsel = 1024; t0 = 0.985f; }  // M ~  737 +/- 27

  // layout: cnt (23040 B, 64B-strided counters) | done[4] (pad to 64) | keybuf | keepkeys | nk_arr
  unsigned* cnt = (unsigned*)ws;
  unsigned* done = (unsigned*)(ws + 23040);
  u64* keybuf = (u64*)(ws + 23104);
  size_t off = 23104 + (size_t)NCLS * capsel * 8;
  u64* keepkeys = (u64*)(ws + off);      off += 288000;
  int* nk_arr = (int*)(ws + off);

  hipMemsetAsync(ws, 0, 23104, stream);
  select_kernel<<<B_ * NCH, 256, 0, stream>>>(cls, keybuf, cnt, capsel, t0);
  nms_kernel<<<NCLS, 512, 0, stream>>>(boxes, cls, keybuf, cnt, done, capsel, t0,
                                       keepkeys, nk_arr, (float*)d_out);
}

// Round 11
// 170.581 us; speedup vs baseline: 1.0951x; 1.0363x over previous
//
#include <hip/hip_runtime.h>
#include <stdint.h>

typedef unsigned long long u64;

#define B_ 4
#define N_ 49104
#define C_ 90
#define NCLS (B_ * C_)        // 360
#define MAXK 100
#define THR 0.01f
#define NBH 288               // hot histogram bins: fine-bins [1760,2048) for scores in (0.93,1)
#define BINLO 1760
#define KCAP 640              // karr: window (<=512) / cold red (512) / merge mk+selk (612)
#define PTGT 448              // per-window target candidate count
#define PCAP 512              // window hard cap
#define ACH 128               // anchors per select block (r7)
#define NCH ((N_ + ACH - 1) / ACH)   // 384
#define CAPC 32               // per-(class, select-block) LDS capacity; ample at t0=0.99 (mean ~1.2)
#define NBIN_M 1280           // merge bins (r7)
#define BINBASE 0x3F6E0000u   // float bits 0.9296875 (valid for all t0 >= 0.93)
#define BINSH_M 10
#define T0 0.99f              // M ~ 491 +/- 22; top-448 examined by greedy (r15: sufficient);
                              // r12/r16 "starvation" was structural (FETCH showed no N-scan storm)

// ---------- exact fp32 math matching the numpy/jax reference ----------
__device__ __forceinline__ float area_of(float y1, float x1, float y2, float x2) {
#pragma clang fp contract(off)
  return (y2 - y1) * (x2 - x1);
}

// Division-free EXACT equivalent of  RN32(inter/denom) > 0.1f.
// denom >= 1e-8 > 0 always. 0.1f = 0x3DCCCCCD (odd mantissa); next up is
// 0x3DCCCCCE (even). Ties-to-even rounds the exact midpoint UP, so
//   RN32(inter/denom) > 0.1f  <=>  inter/denom >= MID,  MID = 26843547/2^28.
// MID has 25 mantissa bits, denom 24 -> MID*(double)denom is EXACT (<=49 bits),
// and (double)inter is exact, so the comparison is bit-exact vs the reference.
#define IOU_MID (26843547.0 / 268435456.0)

// aa = SELECTED (kept) box area, ba = candidate area (reference arg order)
__device__ __forceinline__ bool iou_gt(float ay1, float ax1, float ay2, float ax2, float aa,
                                       float by1, float bx1, float by2, float bx2, float ba) {
#pragma clang fp contract(off)
  float y1 = fmaxf(ay1, by1);
  float x1 = fmaxf(ax1, bx1);
  float y2 = fminf(ay2, by2);
  float x2 = fminf(ax2, bx2);
  float inter = fmaxf(y2 - y1, 0.0f) * fmaxf(x2 - x1, 0.0f);
  float denom = aa + ba - inter + 1e-8f;
  return (double)inter >= IOU_MID * (double)denom;
}

__device__ __forceinline__ u64 umax64(u64 a, u64 b) { return a > b ? a : b; }

__device__ __forceinline__ u64 shfl_xor_u64(u64 v, int m) {
  int lo = __shfl_xor((int)(unsigned)v, m);
  int hi = __shfl_xor((int)(unsigned)(v >> 32), m);
  return ((u64)(unsigned)hi << 32) | (u64)(unsigned)lo;
}

__device__ __forceinline__ int key2bin_m(u64 k) {
  int d = (int)((unsigned)(k >> 32) - BINBASE);
  int bin = d >> BINSH_M;
  if (d < 0) bin = 0;
  if (bin > NBIN_M - 1) bin = NBIN_M - 1;
  return bin;
}

__device__ __forceinline__ int keybin_h(u64 k) {
  int bin = (int)((unsigned)(k >> 44) & 2047) - BINLO;
  if (bin < 0) bin = 0;
  if (bin > NBH - 1) bin = NBH - 1;
  return bin;
}

// ---------- kernel S (r7-verbatim, t0=0.99): slab read -> per-class LDS bins ----------
__global__ __launch_bounds__(256) void select_kernel(const float* __restrict__ cls,
                                                     u64* __restrict__ keybuf,
                                                     unsigned* __restrict__ cnt,
                                                     int capsel, float t0) {
  __shared__ u64 ll[C_ * CAPC];        // 23040 B
  __shared__ unsigned lcnt[C_];
  __shared__ unsigned base_s[C_];
  int blk = blockIdx.x;
  int b = blk / NCH, ch = blk - b * NCH;
  int a0 = ch * ACH;
  int aEnd = a0 + ACH; if (aEnd > N_) aEnd = N_;
  int e0 = a0 * C_;                    // byte offset a0*360: 16B-aligned
  int nelem = (aEnd - a0) * C_;
  int tid = threadIdx.x;

  for (int i = tid; i < C_; i += 256) lcnt[i] = 0u;
  __syncthreads();

  const float4* src4 = (const float4*)(cls + (size_t)b * N_ * C_ + e0);
  int n4 = nelem >> 2;
  for (int i4 = tid; i4 < n4; i4 += 256) {
    float4 v = src4[i4];
#pragma unroll
    for (int j = 0; j < 4; ++j) {
      float s = (&v.x)[j];
      if (s > t0) {
        int e = e0 + i4 * 4 + j;
        unsigned n = (unsigned)e / (unsigned)C_;
        unsigned c = (unsigned)e - n * (unsigned)C_;
        u64 key = ((u64)__float_as_uint(s) << 32) | (u64)(0xFFFFFFFFu - n);
        unsigned pos = atomicAdd(&lcnt[c], 1u);
        if (pos < CAPC) {
          ll[c * CAPC + pos] = key;
        } else {                       // LDS overflow (p ~ 0 at t0=0.99): exact global spill
          unsigned g = (unsigned)(b * C_) + c;
          unsigned gp = atomicAdd(&cnt[g * 16], 1u);
          if (gp < (unsigned)capsel) keybuf[(size_t)g * capsel + gp] = key;
        }
      }
    }
  }
  __syncthreads();

  if (tid < C_) {
    unsigned cc = lcnt[tid]; if (cc > CAPC) cc = CAPC;
    base_s[tid] = atomicAdd(&cnt[(b * C_ + tid) * 16], cc);
  }
  __syncthreads();

  for (int i = tid; i < C_ * CAPC; i += 256) {
    int c = i >> 5, j = i & 31;
    unsigned cc = lcnt[c]; if (cc > CAPC) cc = CAPC;
    if ((unsigned)j < cc) {
      unsigned pos = base_s[c] + (unsigned)j;
      if (pos < (unsigned)capsel)
        keybuf[(size_t)(b * C_ + c) * capsel + pos] = ll[i];
    }
  }
}

// ---------- kernel A (r17-verbatim): lazy-window counting sort + rotating-pop greedy + fused merge ----------
__global__ __launch_bounds__(512) void nms_kernel(const float* __restrict__ boxes,
                                                  const float* __restrict__ cls,
                                                  const u64* __restrict__ keybuf,
                                                  const unsigned* __restrict__ cnt,
                                                  unsigned* __restrict__ done,
                                                  int capsel, float t0,
                                                  u64* __restrict__ keepkeys,
                                                  int* __restrict__ nk_arr,
                                                  float* __restrict__ out) {
  int gcls = blockIdx.x;
  int b = gcls / C_, c = gcls - b * C_;
  __shared__ u64 karr[KCAP];           //  5 KB window keys; cold red; merge mk+selk
  __shared__ unsigned hist[NBH];       //  1.2 KB (drained per-window by scatter)
  __shared__ unsigned sfx[NBH];        //  1.2 KB suffix counts (stable)
  __shared__ unsigned histm[NBIN_M];   //  5 KB merge overlay
  __shared__ unsigned sfxm[NBIN_M];    //  5 KB merge overlay
  __shared__ float4 kb[MAXK];          //  kept boxes
  __shared__ float ka[MAXK];           //  kept areas
  __shared__ unsigned wsum[8];
  __shared__ int sh_cnt[8];            //  per-slice cumulative keep counts
  __shared__ int sh_b1, sh_run, sh_over;
  __shared__ int sh_last, sh_thr;
  __shared__ unsigned sh_cc;
  int tid = threadIdx.x;
  int lane = tid & 63;
  int wid = tid >> 6;

  for (int i = tid; i < MAXK; i += 512) keepkeys[(size_t)gcls * MAXK + i] = 0ull;
  for (int i = tid; i < NBH; i += 512) hist[i] = 0u;
  if (tid == 0) sh_over = 0;
  __syncthreads();

  unsigned Mraw = cnt[gcls * 16];
  bool overflow = (Mraw > (unsigned)capsel);   // p ~ 0: exact full brute force below
  int M = overflow ? 0 : (int)Mraw;

  const u64* src = keybuf + (size_t)gcls * capsel;

  // Phase A: histogram (288 bins); keys cached in registers
  const int PK = 4096 / 512;           // 8 keys/thread (max capsel tier)
  u64 kreg[PK];
#pragma unroll
  for (int q = 0; q < PK; ++q) {
    kreg[q] = 0ull;
    int i = q * 512 + tid;
    if (i < M) {
      kreg[q] = src[i];
      atomicAdd(&hist[keybin_h(kreg[q])], 1u);
    }
  }
  __syncthreads();

  // Phase B: inclusive suffix sum over 288 bins: sfx[bin] = #keys in bins >= bin
  {
    unsigned psum = (tid < NBH) ? hist[NBH - 1 - tid] : 0u;
    unsigned incl = psum;
#pragma unroll
    for (int s = 1; s < 64; s <<= 1) {
      unsigned v = (unsigned)__shfl_up((int)incl, s);
      if (lane >= s) incl += v;
    }
    if (lane == 63 && wid < 5) wsum[wid] = incl;
    __syncthreads();
    if (tid < NBH) {
      unsigned base2 = 0;
      for (int w2 = 0; w2 < wid; ++w2) base2 += wsum[w2];
      sfx[NBH - 1 - tid] = base2 + incl;
    }
  }
  __syncthreads();

  const float4* bx4 = (const float4*)(boxes + (size_t)b * N_ * 4);

  // ---- lazy-window greedy loop ----
  int seen = 0;                        // keeps so far (uniform across block)
  int ext = 0;                         // keys consumed (== sfx[bhi])
  int bhi = NBH;                       // exclusive upper bin bound of next window
  while (ext < M && seen < MAXK) {
    // cut: largest bin b1 < bhi with sfx[b1] >= ext + min(rem, PTGT)
    if (tid == 0) sh_b1 = -1;
    __syncthreads();
    int rem = M - ext;
    int target = rem < PTGT ? rem : PTGT;
    {
      int mymax = -1;
      if (tid < NBH && tid < bhi && (int)sfx[tid] >= ext + target) mymax = tid;
      for (int m = 32; m > 0; m >>= 1) {
        int o = __shfl_xor(mymax, m);
        mymax = o > mymax ? o : mymax;
      }
      if (lane == 0 && mymax >= 0) atomicMax(&sh_b1, mymax);
    }
    __syncthreads();
    if (tid == 0) {
      int b1 = sh_b1;                  // exists: sfx[0] == M >= ext + target
      int run = (int)sfx[b1] - ext;
      int blo = b1;
      if (run > PCAP) {                // fat crossing bin: exclude it
        blo = b1 + 1;
        run = (blo < NBH) ? (int)sfx[blo] - ext : 0;
      }
      if (run == 0) sh_over = 1;       // single bin > PCAP keys (degenerate ties)
      sh_b1 = blo; sh_run = run;
    }
    __syncthreads();
    if (sh_over) break;
    int blo = sh_b1, run = sh_run;

    // scatter bins [blo, bhi) from kreg into karr[0..run)
#pragma unroll
    for (int q = 0; q < PK; ++q) {
      int i = q * 512 + tid;
      if (i < M) {
        u64 k = kreg[q];
        int bin = keybin_h(k);
        if (bin >= blo && bin < bhi) {
          unsigned old = atomicSub(&hist[bin], 1u);
          karr[(int)sfx[bin] - (int)old - ext] = k;
        }
      }
    }
    __syncthreads();

    // rank-permute within each bin -> karr[0..run) fully sorted descending
    {
      u64 mk2 = 0ull; int mt = -1;
      if (tid < run) {
        u64 k = karr[tid];
        int bin = keybin_h(k);
        int hi2 = (int)sfx[bin] - ext;
        int lo2 = (bin >= NBH - 1) ? 0 : ((int)sfx[bin + 1] - ext);
        if (lo2 < 0) lo2 = 0;
        int r = lo2;
        for (int j = lo2; j < hi2; ++j) r += (karr[j] > k);  // keys unique
        mk2 = k; mt = r;
      }
      __syncthreads();
      if (mt >= 0) karr[mt] = mk2;
    }
    __syncthreads();

    // rotating-pop greedy over this window
    {
      bool have = tid < run;
      float4 cb = make_float4(0.f, 0.f, 0.f, 0.f);
      float ca = 0.f;
      if (have) {
        u64 k = karr[tid];
        cb = bx4[0xFFFFFFFFu - (unsigned)(k & 0xFFFFFFFFull)];
        ca = area_of(cb.x, cb.y, cb.z, cb.w);
      }
      // arrival: suppress by keeps [0, seen) — all waves in parallel
      bool dead = !have;
      for (int j = 0; j < seen; ++j) {
        float4 sb = kb[j]; float sa = ka[j];
        dead |= iou_gt(sb.x, sb.y, sb.z, sb.w, sa,
                       cb.x, cb.y, cb.z, cb.w, ca);
      }
      u64 alive = __ballot(!dead);

      int nslice = (run + 63) >> 6;
      for (int s = 0; s < nslice; ++s) {
        if (wid == s) {
          // ---- this wave pops its own slice (r11 single-pop body) ----
          int nkl = seen;
          int slo = s << 6;
          while (alive != 0ull && nkl < MAXK) {
            int bit = __ffsll((long long)alive) - 1;
            float sy1 = __shfl(cb.x, bit);
            float sx1 = __shfl(cb.y, bit);
            float sy2 = __shfl(cb.z, bit);
            float sx2 = __shfl(cb.w, bit);
            float sa  = __shfl(ca,   bit);
            if (lane == 0) {
              u64 key = karr[slo + bit];
              unsigned anchor = 0xFFFFFFFFu - (unsigned)(key & 0xFFFFFFFFull);
              unsigned flat = anchor * C_ + (unsigned)c;
              keepkeys[(size_t)gcls * MAXK + nkl] =
                  (key & 0xFFFFFFFF00000000ull) | (u64)(0xFFFFFFFFu - flat);
              kb[nkl] = make_float4(sy1, sx1, sy2, sx2);
              ka[nkl] = sa;
            }
            ++nkl;
            alive &= ~__ballot(iou_gt(sy1, sx1, sy2, sx2, sa,
                                      cb.x, cb.y, cb.z, cb.w, ca));
            // self-bit always cleared (self-IOU ~ 1 > 0.1)
          }
          if (lane == 0) sh_cnt[s] = nkl;
          seen = nkl;
        }
        __syncthreads();               // publishes kb/ka/sh_cnt[s] to all waves
        int nkNew = (wid == s) ? seen : sh_cnt[s];
        if (nkNew >= MAXK) { seen = nkNew; break; }
        if (wid > s && nkNew > seen) {
          // ---- apply slice-s keeps to own alive mask (parallel across waves) ----
          bool d2 = false;
          for (int j = seen; j < nkNew; ++j) {
            float4 sb = kb[j]; float sa = ka[j];
            d2 |= iou_gt(sb.x, sb.y, sb.z, sb.w, sa,
                         cb.x, cb.y, cb.z, cb.w, ca);
          }
          alive &= __ballot(!d2);
        }
        seen = nkNew;
      }
    }
    ext += run;                        // == sfx[blo]
    bhi = blo;
    __syncthreads();
  }

  // ---- inline exact continuation (cold path; reuses karr as reduction buf) ----
  int nkF = seen;
  if (nkF < MAXK) {
    float teff;
    if (overflow)      teff = 2.0f;
    else if (sh_over)  teff = __uint_as_float(0x3F000000u | ((((unsigned)(bhi + BINLO)) << 12) - 1u));
    else               teff = t0;      // pool exhausted (ext >= M)
    const float* sbase = cls + (size_t)b * N_ * C_ + c;
    const float* bx = boxes + (size_t)b * N_ * 4;
    u64* kkp = keepkeys + (size_t)gcls * MAXK;
    u64* red = karr;                   // karr no longer needed
    int nk2 = nkF;
    while (nk2 < MAXK) {
      u64 best = 0ull;
      for (int n = tid; n < N_; n += 512) {
        float s = sbase[(size_t)n * C_];
        if (s > THR && s <= teff) {
          float y1 = bx[(size_t)n * 4 + 0], x1 = bx[(size_t)n * 4 + 1];
          float y2 = bx[(size_t)n * 4 + 2], x2 = bx[(size_t)n * 4 + 3];
          float ar = area_of(y1, x1, y2, x2);
          bool ov = false;
          for (int j = 0; j < nk2; ++j) {
            float4 kbj = kb[j];
            if (iou_gt(kbj.x, kbj.y, kbj.z, kbj.w, ka[j], y1, x1, y2, x2, ar)) { ov = true; break; }
          }
          if (!ov) {
            u64 key = ((u64)__float_as_uint(s) << 32) | (u64)(0xFFFFFFFFu - (unsigned)n);
            best = umax64(best, key);
          }
        }
      }
      red[tid] = best;
      __syncthreads();
      for (int sft = 256; sft > 0; sft >>= 1) {
        if (tid < sft) red[tid] = umax64(red[tid], red[tid + sft]);
        __syncthreads();
      }
      u64 sel = red[0];
      __syncthreads();
      if (sel == 0ull) {
        if (tid == 0) {  // exhausted before MAXK: reference quirk -> keep[anchor 0] = False
          unsigned target2 = 0xFFFFFFFFu - (unsigned)c;  // anchor 0 -> flat == c
          for (int j = 0; j < nk2; ++j)
            if ((unsigned)(kkp[j] & 0xFFFFFFFFull) == target2) kkp[j] = 0ull;
        }
        break;
      }
      unsigned anchor = 0xFFFFFFFFu - (unsigned)(sel & 0xFFFFFFFFull);
      if (tid == 0) {
        float y1 = bx[(size_t)anchor * 4 + 0], x1 = bx[(size_t)anchor * 4 + 1];
        float y2 = bx[(size_t)anchor * 4 + 2], x2 = bx[(size_t)anchor * 4 + 3];
        kb[nk2] = make_float4(y1, x1, y2, x2);
        ka[nk2] = area_of(y1, x1, y2, x2);
        unsigned flat = anchor * C_ + (unsigned)c;
        kkp[nk2] = (sel & 0xFFFFFFFF00000000ull) | (u64)(0xFFFFFFFFu - flat);
      }
      ++nk2;
      __syncthreads();
    }
    nkF = nk2;
  }
  if (tid == 0) nk_arr[gcls] = nkF;

  // ---- fan-in: last finishing block of batch b runs merge inline ----
  __syncthreads();
  if (tid == 0) {
    __threadfence();                   // release all this block's global writes
    sh_last = (atomicAdd(&done[b], 1u) == (unsigned)(C_ - 1)) ? 1 : 0;
  }
  __syncthreads();
  if (!sh_last) return;
  __threadfence();                     // acquire other blocks' writes

  // ===== merge (histogram threshold + 1-barrier rank sort) =====
  {
    const u64* kk = keepkeys + (size_t)b * C_ * MAXK;
    const int TOT = C_ * MAXK;         // 9000
    u64* mk = karr;                    // [0..512)
    u64* selk = karr + 512;            // [0..MAXK)

    for (int i = tid; i < NBIN_M; i += 512) histm[i] = 0u;
    for (int r = tid; r < MAXK; r += 512) selk[r] = 0ull;
    if (tid == 0) { sh_thr = -1; sh_cc = 0u; }
    __syncthreads();
    for (int i = tid; i < TOT; i += 512) {
      u64 k = kk[i];
      if (k != 0ull) atomicAdd(&histm[key2bin_m(k)], 1u);
    }
    __syncthreads();

    const int Wm = 3;                  // 512*3 >= 1280 bins
    int j0 = tid * Wm;
    unsigned psum = 0;
#pragma unroll
    for (int q = 0; q < Wm; ++q) {
      int bin = NBIN_M - 1 - (j0 + q);
      if (bin >= 0) psum += histm[bin];
    }
    unsigned incl = psum;
#pragma unroll
    for (int s = 1; s < 64; s <<= 1) {
      unsigned v = (unsigned)__shfl_up((int)incl, s);
      if (lane >= s) incl += v;
    }
    if (lane == 63) wsum[wid] = incl;
    __syncthreads();
    unsigned base = incl - psum;
    for (int w2 = 0; w2 < wid; ++w2) base += wsum[w2];
    unsigned running = base;
    int mythr = -1;
#pragma unroll
    for (int q = 0; q < Wm; ++q) {
      int bin = NBIN_M - 1 - (j0 + q);
      if (bin >= 0) {
        running += histm[bin];
        sfxm[bin] = running;
        if (mythr < 0 && running >= (unsigned)MAXK) mythr = bin;
      }
    }
    if (mythr >= 0) atomicMax(&sh_thr, mythr);
    __syncthreads();

    int thr = sh_thr; if (thr < 0) thr = 0;
    unsigned S = sfxm[thr];

    if (S <= 512u) {
      for (int i = tid; i < TOT; i += 512) {
        u64 k = kk[i];
        if (k != 0ull && key2bin_m(k) >= thr) {
          unsigned pos = atomicAdd(&sh_cc, 1u);
          mk[pos] = k;
        }
      }
      __syncthreads();
      // rank sort: keys unique & nonzero -> unique ranks; top-MAXK to selk
      u64 myk = (tid < (int)S) ? mk[tid] : 0ull;
      int r = 0;
      for (int j = 0; j < (int)S; ++j) r += (mk[j] > myk);
      __syncthreads();
      if (tid < (int)S && r < MAXK) selk[r] = myk;
      __syncthreads();
    } else {
      // degenerate tie flood: exact serial tournament on wave 0
      if (wid == 0) {
        int c0 = lane, c1 = lane + 64;
        int len0 = (c0 < C_) ? nk_arr[b * C_ + c0] : 0;
        int len1 = (c1 < C_) ? nk_arr[b * C_ + c1] : 0;
        int h0 = 0, h1 = 0;
        auto fetchc = [&](int cc, int& h, int len) -> u64 {
          while (h < len) {
            u64 k = kk[(size_t)cc * MAXK + h];
            if (k != 0ull) return k;
            ++h;
          }
          return 0ull;
        };
        u64 cand0 = (c0 < C_) ? fetchc(c0, h0, len0) : 0ull;
        u64 cand1 = (c1 < C_) ? fetchc(c1, h1, len1) : 0ull;
        for (int r2 = 0; r2 < MAXK; ++r2) {
          u64 my = umax64(cand0, cand1);
          u64 g = my;
#pragma unroll
          for (int m = 1; m < 64; m <<= 1) g = umax64(g, shfl_xor_u64(g, m));
          if (lane == 0) selk[r2] = g;
          if (g != 0ull && my == g) {
            if (cand0 == g) { ++h0; cand0 = fetchc(c0, h0, len0); }
            else            { ++h1; cand1 = fetchc(c1, h1, len1); }
          }
        }
      }
      __syncthreads();
    }

    for (int r2 = tid; r2 < MAXK; r2 += 512) {
      u64 s = selk[r2];
      float oy1, ox1, oy2, ox2, sc, lb;
      if (s != 0ull) {
        unsigned flat = 0xFFFFFFFFu - (unsigned)(s & 0xFFFFFFFFull);
        unsigned anchor = flat / C_;
        unsigned label = flat - anchor * C_;
        sc = __uint_as_float((unsigned)(s >> 32));
        const float4 bp = ((const float4*)(boxes + (size_t)b * N_ * 4))[anchor];
        oy1 = bp.x; ox1 = bp.y; oy2 = bp.z; ox2 = bp.w;
        lb = (float)label;
      } else {
        oy1 = ox1 = oy2 = ox2 = -1.0f; sc = -1.0f; lb = -1.0f;
      }
      float* bo = out + ((size_t)b * MAXK + r2) * 4;
      bo[0] = oy1; bo[1] = ox1; bo[2] = oy2; bo[3] = ox2;
      out[(size_t)B_ * MAXK * 4 + b * MAXK + r2] = sc;
      out[(size_t)B_ * MAXK * 4 + B_ * MAXK + b * MAXK + r2] = lb;
    }
  }
}

extern "C" void kernel_launch(void* const* d_in, const int* in_sizes, int n_in,
                              void* d_out, int out_size, void* d_ws, size_t ws_size,
                              hipStream_t stream) {
  const float* boxes = (const float*)d_in[0];   // [B,N,4]
  const float* cls = (const float*)d_in[1];     // [B,N,C]
  char* ws = (char*)d_ws;

  // capacity tier by available workspace; t0 = 0.99 for all tiers (M ~ 491)
  int capsel;
  auto need_for = [](int cap) -> size_t {
    return 23104 + (size_t)NCLS * cap * 8 + 288000 + 1440;
  };
  if (ws_size >= need_for(4096))      capsel = 4096;
  else if (ws_size >= need_for(2048)) capsel = 2048;
  else                                capsel = 1024;

  // layout: cnt (23040 B, 64B-strided counters) | done[4] (pad to 64) | keybuf | keepkeys | nk_arr
  unsigned* cnt = (unsigned*)ws;
  unsigned* done = (unsigned*)(ws + 23040);
  u64* keybuf = (u64*)(ws + 23104);
  size_t off = 23104 + (size_t)NCLS * capsel * 8;
  u64* keepkeys = (u64*)(ws + off);      off += 288000;
  int* nk_arr = (int*)(ws + off);

  hipMemsetAsync(ws, 0, 23104, stream);
  select_kernel<<<B_ * NCH, 256, 0, stream>>>(cls, keybuf, cnt, capsel, T0);
  nms_kernel<<<NCLS, 512, 0, stream>>>(boxes, cls, keybuf, cnt, done, capsel, T0,
                                       keepkeys, nk_arr, (float*)d_out);
}